// Round 15
// baseline (15888.055 us; speedup 1.0000x reference)
//
#include <hip/hip_runtime.h>

// HybridQLSTM: B=64, S=2048, D=4 (2x2 conv), H=256, NCLS=2.
// R13 (2nd resubmit; rounds 13-14 were acquisition timeouts, never ran):
// HYBRID gate split -- i,f via register-resident dot2 (R4-proven path),
// g,o via MFMA broadcast-A (R10/R12-proven layout, absmax 0.00195).
//  - vector-only is pinned at the dot2 VALU floor (~2050 cyc/SIMD/step).
//  - all-MFMA can't fit: W_hh (512 KB) ~= the whole VGPR file; R12's LDS
//    spill tiles + in-loop wihb reads gave 7.55e7 bank conflicts + exposed
//    latency at 1 wave/SIMD (5459 us).
//  - capacity split: i,f weights 256 VGPR (dot2, ~1150 cyc) + g,o as 8
//    MFMA tiles/wave (4 reg + 4 LDS = exactly the 128 KB LDS budget,
//    64 MFMA/wave ~= 310 cyc). One thread = one unit: no psum, no per-step
//    wihb LDS traffic (W_ih+bias in 12 regs), A-frags all prefetched,
//    o-frags double-buffered one k ahead (kills the LDS->MFMA dependency).
// Extraction: broadcast-A makes all D rows identical -> lane l holds col
// l&15 of every tile in reg 0 -> unit w*64 + (l>>4)*16 + (l&15) = w*64+l.

#define BB 64
#define SS 2048
#define HH 256

typedef _Float16 f16;
typedef _Float16 h2 __attribute__((ext_vector_type(2)));
typedef _Float16 v8h __attribute__((ext_vector_type(8)));
typedef float f32x4 __attribute__((ext_vector_type(4)));

union V8H { v8h v; h2 p[4]; };

__device__ __forceinline__ float fdot2f(h2 a, h2 b, float c){
#if __has_builtin(__builtin_amdgcn_fdot2)
  return __builtin_amdgcn_fdot2(a, b, c, false);
#else
  return c + (float)a.x*(float)b.x + (float)a.y*(float)b.y;
#endif
}

__device__ __forceinline__ float rcpf_(float x){
#if __has_builtin(__builtin_amdgcn_rcpf)
  return __builtin_amdgcn_rcpf(x);
#else
  return 1.f/x;
#endif
}
__device__ __forceinline__ float sigmf_(float x){ return rcpf_(1.f + __expf(-x)); }
__device__ __forceinline__ float tanhf_(float x){
  x = fminf(fmaxf(x, -15.f), 15.f);
  float e = __expf(2.f*x);
  return (e - 1.f)*rcpf_(e + 1.f);
}
__device__ __forceinline__ h2 mkh2(float a, float b){ h2 r; r.x=(f16)a; r.y=(f16)b; return r; }

// Raw barrier: orders LDS only (lgkmcnt); vmem stays outstanding across steps.
__device__ __forceinline__ void lds_barrier(){
  asm volatile("s_waitcnt lgkmcnt(0)\n\ts_barrier" ::: "memory");
}

// ----------------------------------------------------------------------------
// prep: linear job space.
// seg0 feat (131072), seg1 Bpack g/o (16384), seg2 wihp (1024),
// seg3 w1t (32768), seg4 w2t (32768), seg5 w3p (256).
// total 214272 = 837*256.
// Bpack id: l=id&63, k=(id>>6)&7, tl=(id>>9)&7 (gamma=tl>>2: 0=g,1=o;
//   sub=tl&3), w=(id>>12)&3. 16B entry = W_hh[n][kk..kk+7],
//   n = (2+gamma)*256 + w*64 + sub*16 + (l&15),  kk = k*32 + (l>>4)*8.
// wihp entry (R4 layout): id=4u+copy, 16 f16 = {i,f,g,o}[0..3]; biasp float4.
// ----------------------------------------------------------------------------
__global__ void prep_kernel(
    const float* __restrict__ x, const float* __restrict__ conv_w, const float* __restrict__ conv_b,
    const float* __restrict__ w_ih, const float* __restrict__ w_hh,
    const float* __restrict__ b_ih, const float* __restrict__ b_hh,
    const float* __restrict__ w1, const float* __restrict__ w2, const float* __restrict__ w3,
    f16* __restrict__ feat2, f16* __restrict__ Bpack, f16* __restrict__ wihp,
    float* __restrict__ biasp, f16* __restrict__ w1t, f16* __restrict__ w2t, f16* __restrict__ w3p)
{
  int id = blockIdx.x*256 + threadIdx.x;
  if (id < BB*SS){
    float4 xv = *(const float4*)(x + (size_t)id*4);
    float f0 = sigmf_(xv.x*conv_w[0] + conv_b[0]);
    float f1 = sigmf_(xv.y*conv_w[1] + conv_b[1]);
    float f2 = sigmf_(xv.z*conv_w[2] + conv_b[2]);
    float f3 = sigmf_(xv.w*conv_w[3] + conv_b[3]);
    h2* o = (h2*)feat2 + (size_t)id*2;
    o[0] = mkh2(f0,f1); o[1] = mkh2(f2,f3);
    return;
  }
  id -= BB*SS;
  if (id < 16384){
    int l = id & 63, k = (id>>6)&7, tl = (id>>9)&7, w = (id>>12)&3;
    int gamma = tl >> 2, sub = tl & 3;
    int n  = (2+gamma)*256 + w*64 + sub*16 + (l&15);
    int kk = k*32 + ((l>>4))*8;
    const float* src = w_hh + (size_t)n*256 + kk;
    v8h o;
    #pragma unroll
    for (int j=0;j<8;j++) o[j] = (f16)src[j];
    *((v8h*)Bpack + id) = o;
    return;
  }
  id -= 16384;
  if (id < 1024){
    int u = id >> 2;
    f16* o = wihp + (size_t)id*16;
    float bb[4];
    #pragma unroll
    for (int i=0;i<4;i++){
      int row = u + 256*i;
      o[i*4+0] = (f16)w_ih[row*4+0];
      o[i*4+1] = (f16)w_ih[row*4+1];
      o[i*4+2] = (f16)w_ih[row*4+2];
      o[i*4+3] = (f16)w_ih[row*4+3];
      bb[i] = b_ih[row] + b_hh[row];
    }
    *(float4*)(biasp + (size_t)id*4) = make_float4(bb[0],bb[1],bb[2],bb[3]);
    return;
  }
  id -= 1024;
  if (id < 32768){ // w1t[kp*256+n] = half2(w1[n][2kp], w1[n][2kp+1])
    int kp = id >> 8, n = id & 255;
    w1t[(size_t)id*2+0] = (f16)w1[(size_t)n*256 + 2*kp];
    w1t[(size_t)id*2+1] = (f16)w1[(size_t)n*256 + 2*kp+1];
    return;
  }
  id -= 32768;
  if (id < 32768){
    int kp = id >> 8, n = id & 255;
    w2t[(size_t)id*2+0] = (f16)w2[(size_t)n*256 + 2*kp];
    w2t[(size_t)id*2+1] = (f16)w2[(size_t)n*256 + 2*kp+1];
    return;
  }
  id -= 32768;
  if (id < 256){
    int kp = id >> 1, cls = id & 1;
    w3p[(size_t)id*2+0] = (f16)w3[(size_t)cls*256 + 2*kp];
    w3p[(size_t)id*2+1] = (f16)w3[(size_t)cls*256 + 2*kp+1];
  }
}

// ----------------------------------------------------------------------------
// LSTM hybrid. 64 blocks x 256 threads (4 waves, 1/SIMD, 512-VGPR cap).
// Thread t = unit u (0..255); wave w = t>>6; l = t&63; grp = l>>4; c = l&15.
// LDS (dynamic 132096 B): [0..131072) o-tile B-frags (4 waves x 4 tiles x
// 8 k x 1024 B); [131072..132096) h double buffer 2 x 256 f16.
// ----------------------------------------------------------------------------
#define LDS_H 131072
#define GLDS_BYTES 132096

__global__ __launch_bounds__(256, 1) void lstm_kernel(
    const float* __restrict__ w_hh, const f16* __restrict__ Bpack,
    const f16* __restrict__ feat2, const f16* __restrict__ wihp,
    const float* __restrict__ biasp, f16* __restrict__ hbuf)
{
  extern __shared__ __align__(16) char glds[];
  const int b = blockIdx.x, tid = threadIdx.x;
  const int u = tid, w = tid >> 6, l = tid & 63;
  const int grp = l >> 4;

  // --- i,f weights: full rows u and u+256, register-resident (256 VGPR) ---
  h2 wi[128], wf[128];
  {
    const float* si = w_hh + (size_t)u*256;
    const float* sf = w_hh + (size_t)(u+256)*256;
    #pragma unroll
    for (int cc=0; cc<32; cc++){
      float4 q0 = *(const float4*)(si + cc*8);
      float4 q1 = *(const float4*)(si + cc*8 + 4);
      wi[cc*4+0] = mkh2(q0.x,q0.y); wi[cc*4+1] = mkh2(q0.z,q0.w);
      wi[cc*4+2] = mkh2(q1.x,q1.y); wi[cc*4+3] = mkh2(q1.z,q1.w);
      q0 = *(const float4*)(sf + cc*8);
      q1 = *(const float4*)(sf + cc*8 + 4);
      wf[cc*4+0] = mkh2(q0.x,q0.y); wf[cc*4+1] = mkh2(q0.z,q0.w);
      wf[cc*4+2] = mkh2(q1.x,q1.y); wf[cc*4+3] = mkh2(q1.z,q1.w);
    }
  }
  // --- g tiles (tl 0..3) -> registers; o tiles (tl 4..7) -> LDS ---
  const v8h* bp = (const v8h*)Bpack + (size_t)w*4096;   // + (tl*8+k)*64 + l
  v8h bg[4][8];
  #pragma unroll
  for (int sub=0; sub<4; sub++)
    #pragma unroll
    for (int k=0; k<8; k++)
      bg[sub][k] = bp[(sub*8+k)*64 + l];
  {
    f16* bl = (f16*)glds + (size_t)w*16384;
    #pragma unroll
    for (int sub=0; sub<4; sub++)
      #pragma unroll
      for (int k=0; k<8; k++){
        v8h v = bp[((4+sub)*8+k)*64 + l];
        *(v8h*)(bl + (sub*8+k)*512 + l*8) = v;
      }
  }
  // --- W_ih + bias for unit u (step-invariant, registers) ---
  h2 wx[8];
  {
    const h2* p = (const h2*)(wihp + (size_t)u*64);   // entry id = 4u
    #pragma unroll
    for (int j=0;j<8;j++) wx[j] = p[j];
  }
  const float4 bsv = *(const float4*)(biasp + (size_t)u*16);

  f16* hb = (f16*)(glds + LDS_H);
  hb[tid] = (f16)0.f; hb[256+tid] = (f16)0.f;
  __syncthreads();

  const f16* bol = (const f16*)glds + (size_t)w*16384 + l*8;  // o-frag base
  const h2* fp = (const h2*)feat2 + (size_t)b*SS*2;
  f16* hrow = hbuf + (size_t)b*SS*HH;
  float cst = 0.f;
  int buf = 0;
  const f32x4 Z4 = {0.f,0.f,0.f,0.f};

  for (int s=0; s<SS; ++s){
    h2 f01 = fp[0], f23 = fp[1]; fp += 2;        // uniform; hides under work
    const f16* hbase = hb + buf*256;

    // ---- prefetch all 8 A-frags (h broadcast rows) ----
    const f16* hA = hbase + grp*8;
    v8h a0 = *(const v8h*)(hA + 0*32);
    v8h a1 = *(const v8h*)(hA + 1*32);
    v8h a2 = *(const v8h*)(hA + 2*32);
    v8h a3 = *(const v8h*)(hA + 3*32);
    v8h a4 = *(const v8h*)(hA + 4*32);
    v8h a5 = *(const v8h*)(hA + 5*32);
    v8h a6 = *(const v8h*)(hA + 6*32);
    v8h a7 = *(const v8h*)(hA + 7*32);

    // ---- MFMA g,o: 8 tiles, o-frags double-buffered one k ahead ----
    f32x4 aG0=Z4, aG1=Z4, aG2=Z4, aG3=Z4;
    f32x4 aO0=Z4, aO1=Z4, aO2=Z4, aO3=Z4;
    v8h oA0,oA1,oA2,oA3, oB0,oB1,oB2,oB3;
    oA0 = *(const v8h*)(bol + (0*8+0)*512);
    oA1 = *(const v8h*)(bol + (1*8+0)*512);
    oA2 = *(const v8h*)(bol + (2*8+0)*512);
    oA3 = *(const v8h*)(bol + (3*8+0)*512);
#define MFMA_K(ak, k, OC0,OC1,OC2,OC3, ON0,ON1,ON2,ON3, kn) \
    ON0 = *(const v8h*)(bol + (0*8+(kn))*512); \
    ON1 = *(const v8h*)(bol + (1*8+(kn))*512); \
    ON2 = *(const v8h*)(bol + (2*8+(kn))*512); \
    ON3 = *(const v8h*)(bol + (3*8+(kn))*512); \
    aG0 = __builtin_amdgcn_mfma_f32_16x16x32_f16(ak, bg[0][k], aG0, 0,0,0); \
    aG1 = __builtin_amdgcn_mfma_f32_16x16x32_f16(ak, bg[1][k], aG1, 0,0,0); \
    aG2 = __builtin_amdgcn_mfma_f32_16x16x32_f16(ak, bg[2][k], aG2, 0,0,0); \
    aG3 = __builtin_amdgcn_mfma_f32_16x16x32_f16(ak, bg[3][k], aG3, 0,0,0); \
    aO0 = __builtin_amdgcn_mfma_f32_16x16x32_f16(ak, OC0, aO0, 0,0,0); \
    aO1 = __builtin_amdgcn_mfma_f32_16x16x32_f16(ak, OC1, aO1, 0,0,0); \
    aO2 = __builtin_amdgcn_mfma_f32_16x16x32_f16(ak, OC2, aO2, 0,0,0); \
    aO3 = __builtin_amdgcn_mfma_f32_16x16x32_f16(ak, OC3, aO3, 0,0,0);
    MFMA_K(a0, 0, oA0,oA1,oA2,oA3, oB0,oB1,oB2,oB3, 1)
    MFMA_K(a1, 1, oB0,oB1,oB2,oB3, oA0,oA1,oA2,oA3, 2)
    MFMA_K(a2, 2, oA0,oA1,oA2,oA3, oB0,oB1,oB2,oB3, 3)
    MFMA_K(a3, 3, oB0,oB1,oB2,oB3, oA0,oA1,oA2,oA3, 4)
    MFMA_K(a4, 4, oA0,oA1,oA2,oA3, oB0,oB1,oB2,oB3, 5)
    MFMA_K(a5, 5, oB0,oB1,oB2,oB3, oA0,oA1,oA2,oA3, 6)
    MFMA_K(a6, 6, oA0,oA1,oA2,oA3, oB0,oB1,oB2,oB3, 7)
    MFMA_K(a7, 7, oB0,oB1,oB2,oB3, oA0,oA1,oA2,oA3, 0)
#undef MFMA_K

    // ---- i,f dots: broadcast h reads, 4 independent chains per gate ----
    float ai0=0.f, ai1=0.f, ai2=0.f, ai3=0.f;
    float af0=0.f, af1=0.f, af2=0.f, af3=0.f;
    const v8h* hbb = (const v8h*)hbase;       // uniform address -> broadcast
    #pragma unroll
    for (int cc=0; cc<32; cc++){
      V8H hh; hh.v = hbb[cc];
      ai0 = fdot2f(wi[cc*4+0], hh.p[0], ai0);
      ai1 = fdot2f(wi[cc*4+1], hh.p[1], ai1);
      ai2 = fdot2f(wi[cc*4+2], hh.p[2], ai2);
      ai3 = fdot2f(wi[cc*4+3], hh.p[3], ai3);
      af0 = fdot2f(wf[cc*4+0], hh.p[0], af0);
      af1 = fdot2f(wf[cc*4+1], hh.p[1], af1);
      af2 = fdot2f(wf[cc*4+2], hh.p[2], af2);
      af3 = fdot2f(wf[cc*4+3], hh.p[3], af3);
    }

    // ---- extract g,o for unit u = w*64 + grp*16 + c = w*64 + l ----
    float pg = (grp==0) ? aG0[0] : (grp==1) ? aG1[0] : (grp==2) ? aG2[0] : aG3[0];
    float po = (grp==0) ? aO0[0] : (grp==1) ? aO1[0] : (grp==2) ? aO2[0] : aO3[0];

    // ---- pre-activations: bias + input projection ----
    float pi = fdot2f(wx[1], f23, fdot2f(wx[0], f01, (ai0+ai1)+(ai2+ai3) + bsv.x));
    float pf = fdot2f(wx[3], f23, fdot2f(wx[2], f01, (af0+af1)+(af2+af3) + bsv.y));
    pg = fdot2f(wx[5], f23, fdot2f(wx[4], f01, pg + bsv.z));
    po = fdot2f(wx[7], f23, fdot2f(wx[6], f01, po + bsv.w));

    // ---- cell ----
    float iv = sigmf_(pi), fv = sigmf_(pf), gv = tanhf_(pg), ov = sigmf_(po);
    cst = fv*cst + iv*gv;
    float hn = ov*tanhf_(cst);
    f16 hv = (f16)hn;
    hb[(buf^1)*256 + u] = hv;     // next step's h
    hrow[u] = hv;                 // global, fire-and-forget
    hrow += HH;
    lds_barrier();                // lgkm-only; vmem floats across steps
    buf ^= 1;
  }
}

// ----------------------------------------------------------------------------
// classifier: 16 rows per 256-thread block; 4x4 register tile per thread.
// Rows padded to 20 h2 (80 B): v8h reads stay 16B-aligned, dst writes 16-way
// instead of 64-way conflicts.
// ----------------------------------------------------------------------------
__device__ __forceinline__ void fc_layer(const h2 (*src)[20], h2 (*dst)[20],
                                         const f16* __restrict__ wt,
                                         const float* __restrict__ bias, int t)
{
  const int rg = t >> 6;           // row group 0..3
  const int c0 = (t & 63) * 4;     // 4 output cols
  float acc[4][4];
  #pragma unroll
  for (int r=0;r<4;r++){ acc[r][0]=0.f; acc[r][1]=0.f; acc[r][2]=0.f; acc[r][3]=0.f; }
  #pragma unroll 4
  for (int kp=0; kp<128; kp++){
    V8H wv; wv.v = *(const v8h*)(wt + ((size_t)kp*256 + c0)*2);
    V8H rv; rv.v = *(const v8h*)(&src[kp][rg*4]);
    #pragma unroll
    for (int r=0;r<4;r++)
      #pragma unroll
      for (int cc=0;cc<4;cc++)
        acc[r][cc] = fdot2f(rv.p[r], wv.p[cc], acc[r][cc]);
  }
  const float4 bv = *(const float4*)(bias + c0);
  #pragma unroll
  for (int r=0;r<4;r++){
    float o0 = fmaxf(acc[r][0]+bv.x, 0.f);
    float o1 = fmaxf(acc[r][1]+bv.y, 0.f);
    float o2 = fmaxf(acc[r][2]+bv.z, 0.f);
    float o3 = fmaxf(acc[r][3]+bv.w, 0.f);
    dst[(c0>>1)  ][rg*4+r] = mkh2(o0,o1);
    dst[(c0>>1)+1][rg*4+r] = mkh2(o2,o3);
  }
}

__global__ __launch_bounds__(256) void cls_kernel(
    const f16* __restrict__ hbuf, const f16* __restrict__ w1t, const f16* __restrict__ w2t,
    const f16* __restrict__ w3p, const float* __restrict__ b1, const float* __restrict__ b2,
    const float* __restrict__ b3, float* __restrict__ out)
{
  __shared__ __align__(16) h2 rlA[128][20];
  __shared__ __align__(16) h2 rlB[128][20];
  const int t = threadIdx.x;
  const size_t R = (size_t)blockIdx.x * 16;
  {
    int r = t >> 4, seg = t & 15;
    const v8h* src = (const v8h*)(hbuf + (R + r)*HH + seg*16);
    V8H aH; aH.v = src[0];
    V8H bH; bH.v = src[1];
    int kp0 = seg*8;
    #pragma unroll
    for (int j=0;j<4;j++) rlA[kp0+j  ][r] = aH.p[j];
    #pragma unroll
    for (int j=0;j<4;j++) rlA[kp0+4+j][r] = bH.p[j];
  }
  __syncthreads();
  fc_layer(rlA, rlB, w1t, b1, t);
  __syncthreads();
  fc_layer(rlB, rlA, w2t, b2, t);
  __syncthreads();
  if (t < 32){
    int r = t >> 1, cls = t & 1;
    float acc = b3[cls];
    const h2* w3h = (const h2*)w3p;
    #pragma unroll 8
    for (int kp=0; kp<128; kp++)
      acc = fdot2f(rlA[kp][r], w3h[kp*2 + cls], acc);
    out[(R + r)*2 + cls] = acc;
  }
}

// ----------------------------------------------------------------------------
extern "C" void kernel_launch(void* const* d_in, const int* in_sizes, int n_in,
                              void* d_out, int out_size, void* d_ws, size_t ws_size,
                              hipStream_t stream) {
  const float* x      = (const float*)d_in[0];
  const float* conv_w = (const float*)d_in[1];
  const float* conv_b = (const float*)d_in[2];
  const float* w_ih   = (const float*)d_in[3];
  const float* w_hh   = (const float*)d_in[4];
  const float* b_ih   = (const float*)d_in[5];
  const float* b_hh   = (const float*)d_in[6];
  const float* w1     = (const float*)d_in[7];
  const float* b1     = (const float*)d_in[8];
  const float* w2     = (const float*)d_in[9];
  const float* b2     = (const float*)d_in[10];
  const float* w3     = (const float*)d_in[11];
  const float* b3     = (const float*)d_in[12];

  char* ws = (char*)d_ws;
  f16*   feat2   = (f16*)  (ws + 0x000000);  // 1 MB
  f16*   Bpack   = (f16*)  (ws + 0x100000);  // 256 KB (g,o fragment order)
  f16*   wihp    = (f16*)  (ws + 0x140000);  // 32 KB
  float* biasp   = (float*)(ws + 0x148000);  // 16 KB
  f16*   w1t     = (f16*)  (ws + 0x14C000);  // 128 KB
  f16*   w2t     = (f16*)  (ws + 0x16C000);  // 128 KB
  f16*   w3p     = (f16*)  (ws + 0x18C000);  // 1 KB
  f16*   hbuf    = (f16*)  (ws + 0x190000);  // 64 MB

  (void)hipFuncSetAttribute((const void*)lstm_kernel,
                            hipFuncAttributeMaxDynamicSharedMemorySize, GLDS_BYTES);

  prep_kernel<<<837, 256, 0, stream>>>(x, conv_w, conv_b, w_ih, w_hh, b_ih, b_hh,
                                       w1, w2, w3,
                                       feat2, Bpack, wihp, biasp, w1t, w2t, w3p);
  lstm_kernel<<<BB, 256, GLDS_BYTES, stream>>>(w_hh, Bpack, feat2, wihp, biasp, hbuf);
  cls_kernel<<<(BB*SS)/16, 256, 0, stream>>>(hbuf, w1t, w2t, w3p, b1, b2, b3, (float*)d_out);
}